// Round 10
// baseline (189.589 us; speedup 1.0000x reference)
//
#include <hip/hip_runtime.h>
#include <hip/hip_fp16.h>
#include <math.h>

// GCN 2-layer (DGL GraphConv norm='both'). CSR via two-level MSD counting sort,
// zero per-edge global atomics. Round-10 changes vs round 9:
//   - partition: ONE edge sweep (regs stage 16 e/thread), both hists+scatters
//   - srcPart stored as bytes (0.8MB vs 3.2MB)
//   - finalize writes out_norm (float); featw1 runs post-finalize and bakes
//     out_norm into featp -> agg1 inner loop is pure 16B gathers again
// Pipeline:
//   hist(196 blk) -> scan_bins(1 blk) -> partition(196 blk) -> finalize(392 blk)
//   -> featw1 -> agg1 (wave/node, 8x8 lanes, unroll-2) -> agg2 (16 lanes/node)
// Requires N <= 131072 (src in 17 bits of packed word). N=50000.

#define BS 256
#define EPB 4096   // edges per partition block (16 iters of 256)

// ---- A: per-block LDS hist of dst>>8 and src>>8 -> global bin counts ----
__global__ void hist_kernel(const int* __restrict__ src, const int* __restrict__ dst,
                            int* __restrict__ dstBinCount, int* __restrict__ srcBinCount,
                            int E, int NB) {
    __shared__ int histD[256];
    __shared__ int histS[256];
    int tid = threadIdx.x;
    histD[tid] = 0; histS[tid] = 0;
    __syncthreads();
    int base = blockIdx.x * EPB;
    #pragma unroll
    for (int it = 0; it < EPB / BS; it++) {
        int e = base + it * BS + tid;
        if (e < E) {
            atomicAdd(&histD[dst[e] >> 8], 1);
            atomicAdd(&histS[src[e] >> 8], 1);
        }
    }
    __syncthreads();
    if (tid < NB) {
        if (histD[tid]) atomicAdd(&dstBinCount[tid], histD[tid]);
        if (histS[tid]) atomicAdd(&srcBinCount[tid], histS[tid]);
    }
}

// ---- C0: scan both NB-bin count arrays (tiny, 1 block) ----
__global__ void scan_bins_kernel(const int* __restrict__ dstBinCount, const int* __restrict__ srcBinCount,
                                 int* __restrict__ dstBinBase, int* __restrict__ srcBinBase,
                                 int* __restrict__ dstCursor, int* __restrict__ srcCursor, int NB) {
    __shared__ int s[256];
    int t = threadIdx.x;
    int v = (t < NB) ? dstBinCount[t] : 0;
    s[t] = v; __syncthreads();
    for (int off = 1; off < 256; off <<= 1) {
        int u = (t >= off) ? s[t - off] : 0; __syncthreads();
        s[t] += u; __syncthreads();
    }
    if (t < NB) {
        int ex = s[t] - v;
        dstBinBase[t] = ex; dstCursor[t] = ex;
        if (t == NB - 1) dstBinBase[NB] = s[t];
    }
    __syncthreads();
    v = (t < NB) ? srcBinCount[t] : 0;
    s[t] = v; __syncthreads();
    for (int off = 1; off < 256; off <<= 1) {
        int u = (t >= off) ? s[t - off] : 0; __syncthreads();
        s[t] += u; __syncthreads();
    }
    if (t < NB) {
        int ex = s[t] - v;
        srcBinBase[t] = ex; srcCursor[t] = ex;
        if (t == NB - 1) srcBinBase[NB] = s[t];
    }
}

// ---- B: single-sweep partition; edges staged in registers ----
__global__ void partition_kernel(const int* __restrict__ src, const int* __restrict__ dst,
                                 int* __restrict__ dstCursor, int* __restrict__ srcCursor,
                                 int* __restrict__ packed, unsigned char* __restrict__ srcPart,
                                 int E, int NB) {
    __shared__ int curD[256];
    __shared__ int curS[256];
    int tid = threadIdx.x;
    int base = blockIdx.x * EPB;
    int dv[EPB / BS], sv[EPB / BS];
    curD[tid] = 0; curS[tid] = 0;
    __syncthreads();
    #pragma unroll
    for (int it = 0; it < EPB / BS; it++) {
        int e = base + it * BS + tid;
        if (e < E) {
            dv[it] = dst[e]; sv[it] = src[e];
            atomicAdd(&curD[dv[it] >> 8], 1);
            atomicAdd(&curS[sv[it] >> 8], 1);
        } else dv[it] = -1;
    }
    __syncthreads();
    int hD = curD[tid], hS = curS[tid];
    int rbD = (tid < NB && hD) ? atomicAdd(&dstCursor[tid], hD) : 0;
    int rbS = (tid < NB && hS) ? atomicAdd(&srcCursor[tid], hS) : 0;
    __syncthreads();
    curD[tid] = rbD; curS[tid] = rbS;
    __syncthreads();
    #pragma unroll
    for (int it = 0; it < EPB / BS; it++) {
        if (dv[it] >= 0) {
            int d = dv[it], s2 = sv[it];
            int pos = atomicAdd(&curD[d >> 8], 1);
            packed[pos] = s2 | ((d & 255) << 17);
            int pos2 = atomicAdd(&curS[s2 >> 8], 1);
            srcPart[pos2] = (unsigned char)(s2 & 255);
        }
    }
}

// ---- D: per-bin finalize: dst bins -> in_deg/row_start/csr_src; src bins -> out_norm ----
__global__ void finalize_kernel(const int* __restrict__ dstBinBase, const int* __restrict__ srcBinBase,
                                const int* __restrict__ packed, const unsigned char* __restrict__ srcPart,
                                int* __restrict__ csr_src, int* __restrict__ in_deg,
                                int* __restrict__ row_start, float* __restrict__ out_norm,
                                int N, int NB) {
    __shared__ int hist[256];
    __shared__ int sc[256];
    int tid = threadIdx.x;
    int b = blockIdx.x;
    if (b < NB) {
        int lo = dstBinBase[b], hi = dstBinBase[b + 1];
        hist[tid] = 0; __syncthreads();
        for (int i = lo + tid; i < hi; i += BS)
            atomicAdd(&hist[(packed[i] >> 17) & 255], 1);
        __syncthreads();
        int v = hist[tid];
        sc[tid] = v; __syncthreads();
        for (int off = 1; off < 256; off <<= 1) {
            int u = (tid >= off) ? sc[tid - off] : 0; __syncthreads();
            sc[tid] += u; __syncthreads();
        }
        int ex = sc[tid] - v;          // exclusive within bin
        int n = b * 256 + tid;
        if (n < N) { in_deg[n] = v; row_start[n] = lo + ex; }
        sc[tid] = lo + ex;             // becomes the scatter cursor
        __syncthreads();
        for (int i = lo + tid; i < hi; i += BS) {
            int pv = packed[i];
            int pos = atomicAdd(&sc[(pv >> 17) & 255], 1);
            csr_src[pos] = pv & 0x1FFFF;
        }
    } else {
        int sb = b - NB;
        int lo = srcBinBase[sb], hi = srcBinBase[sb + 1];
        hist[tid] = 0; __syncthreads();
        for (int i = lo + tid; i < hi; i += BS)
            atomicAdd(&hist[srcPart[i]], 1);
        __syncthreads();
        int n = sb * 256 + tid;
        if (n < N) out_norm[n] = rsqrtf(fmaxf((float)hist[tid], 1.0f));
    }
}

// ---- featw1: featp = fp16(out_norm * (feat @ W1)); one wave/row ----
__global__ void featw1_kernel(const float* __restrict__ feat,
                              const float* __restrict__ W1,
                              const float* __restrict__ out_norm,
                              __half* __restrict__ featp, int N) {
    __shared__ float w[64 * 64];
    int tid = threadIdx.x;
    for (int i = tid; i < 64 * 16; i += BS)
        ((float4*)w)[i] = ((const float4*)W1)[i];
    __syncthreads();
    int wave = tid >> 6, lane = tid & 63;
    int row = blockIdx.x * 4 + wave;
    if (row >= N) return;
    const float4* fr = (const float4*)(feat + (size_t)row * 64);
    float acc = 0.0f;
    #pragma unroll
    for (int k4 = 0; k4 < 16; k4++) {
        float4 a = fr[k4];                         // wave-uniform broadcast
        acc += a.x * w[(4 * k4 + 0) * 64 + lane];  // lane stride-1: conflict-free
        acc += a.y * w[(4 * k4 + 1) * 64 + lane];
        acc += a.z * w[(4 * k4 + 2) * 64 + lane];
        acc += a.w * w[(4 * k4 + 3) * 64 + lane];
    }
    featp[(size_t)row * 64 + lane] = __float2half(out_norm[row] * acc);
}

// ---- agg1: one wave/node; 8 edge-groups x 8 chunks, unroll-2; pure gathers ----
__global__ void csr_agg1_kernel(const int* __restrict__ row_start, const int* __restrict__ in_deg,
                                const int* __restrict__ csr_src,
                                const __half* __restrict__ featp,
                                const float* __restrict__ b1, const float* __restrict__ W2,
                                const float* __restrict__ out_norm,
                                float* __restrict__ s_buf, int N) {
    int gid = blockIdx.x * blockDim.x + threadIdx.x;
    int n = gid >> 6;
    if (n >= N) return;
    int lane = threadIdx.x & 63;
    int g = lane >> 3;   // edge slot within batch of 8
    int l = lane & 7;    // feature chunk: features [8l, 8l+8)
    int start = row_start[n];
    int deg = in_deg[n];
    float acc[8] = {0, 0, 0, 0, 0, 0, 0, 0};
    const uint4* fp4 = (const uint4*)featp;
    for (int j = 0; j < deg; j += 16) {
        int e0 = j + g;
        int e1 = j + 8 + g;
        bool p0 = e0 < deg;
        bool p1 = e1 < deg;
        int sn0 = p0 ? csr_src[start + e0] : 0;
        int sn1 = p1 ? csr_src[start + e1] : 0;
        uint4 q0 = {0, 0, 0, 0}, q1 = {0, 0, 0, 0};
        if (p0) q0 = fp4[(size_t)sn0 * 8 + l];   // two independent 16B gathers
        if (p1) q1 = fp4[(size_t)sn1 * 8 + l];
        const __half2* h0 = (const __half2*)&q0;
        const __half2* h1 = (const __half2*)&q1;
        #pragma unroll
        for (int c = 0; c < 4; c++) {
            float2 f0 = __half22float2(h0[c]);
            float2 f1 = __half22float2(h1[c]);
            acc[2 * c]     += f0.x + f1.x;
            acc[2 * c + 1] += f0.y + f1.y;
        }
    }
    #pragma unroll
    for (int off = 8; off < 64; off <<= 1) {
        #pragma unroll
        for (int c = 0; c < 8; c++)
            acc[c] += __shfl_xor(acc[c], off, 64);
    }
    float inn = rsqrtf(fmaxf((float)deg, 1.0f));
    float v = 0.0f;
    #pragma unroll
    for (int c = 0; c < 8; c++) {
        float h = fmaxf(inn * acc[c] + b1[l * 8 + c], 0.0f);
        v += h * W2[l * 8 + c];
    }
    #pragma unroll
    for (int off = 1; off < 8; off <<= 1)
        v += __shfl_xor(v, off, 64);
    if (lane == 0)
        s_buf[n] = out_norm[n] * v;
}

// ---- agg2: 16 lanes/node, unroll-2, sigmoid -> out ----
__global__ void csr_agg2_kernel(const int* __restrict__ row_start, const int* __restrict__ in_deg,
                                const int* __restrict__ csr_src,
                                const float* __restrict__ s_buf, const float* __restrict__ b2,
                                float* __restrict__ out, int N) {
    int gid = blockIdx.x * blockDim.x + threadIdx.x;
    int n = gid >> 4;
    if (n >= N) return;
    int sub = gid & 15;
    int start = row_start[n];
    int deg = in_deg[n];
    float a = 0.0f;
    for (int j = sub; j < deg; j += 32) {
        int j1 = j + 16;
        int i0 = csr_src[start + j];
        int i1 = (j1 < deg) ? csr_src[start + j1] : 0;
        float v0 = s_buf[i0];
        float v1 = (j1 < deg) ? s_buf[i1] : 0.0f;
        a += v0 + v1;
    }
    #pragma unroll
    for (int off = 1; off < 16; off <<= 1)
        a += __shfl_xor(a, off, 64);
    if (sub == 0) {
        float x = rsqrtf(fmaxf((float)deg, 1.0f)) * a + b2[0];
        out[n] = 1.0f / (1.0f + expf(-x));
    }
}

extern "C" void kernel_launch(void* const* d_in, const int* in_sizes, int n_in,
                              void* d_out, int out_size, void* d_ws, size_t ws_size,
                              hipStream_t stream) {
    const float* feat = (const float*)d_in[0];
    const float* W1   = (const float*)d_in[1];
    const float* b1   = (const float*)d_in[2];
    const float* W2   = (const float*)d_in[3];
    const float* b2   = (const float*)d_in[4];
    const int* src = (const int*)d_in[5];
    const int* dst = (const int*)d_in[6];
    float* out = (float*)d_out;

    const int N  = in_sizes[0] / 64;       // 50000
    const int E  = in_sizes[5];            // 800000
    const int NB = (N + 255) >> 8;         // 196 bins of 256 nodes
    const int T  = (E + EPB - 1) / EPB;    // 196 partition blocks

    // workspace: int region | srcPart bytes | fp16 featp (16B-aligned) | floats
    int* wsi = (int*)d_ws;
    int* dstBinCount = wsi;                          // NB  (zeroed together)
    int* srcBinCount = dstBinCount + NB;             // NB
    int* dstBinBase  = srcBinCount + NB;             // NB+1
    int* srcBinBase  = dstBinBase + NB + 1;          // NB+1
    int* dstCursor   = srcBinBase + NB + 1;          // NB
    int* srcCursor   = dstCursor + NB;               // NB
    int* in_deg      = srcCursor + NB;               // N
    int* row_start   = in_deg + N;                   // N
    int* packed      = row_start + N;                // E
    int* csr_src     = packed + E;                   // E
    unsigned char* srcPart = (unsigned char*)(csr_src + E);   // E bytes
    size_t off_b = ((size_t)(6 * NB + 2) + 2 * (size_t)N + 2 * (size_t)E) * sizeof(int) + (size_t)E;
    off_b = (off_b + 15) & ~(size_t)15;
    __half* featp   = (__half*)((char*)d_ws + off_b);                       // 64N fp16
    float*  out_norm = (float*)((char*)d_ws + off_b + (size_t)64 * N * sizeof(__half)); // N
    float*  s_buf    = out_norm + N;                                        // N

    hipMemsetAsync(dstBinCount, 0, (size_t)2 * NB * sizeof(int), stream);

    hist_kernel<<<T, BS, 0, stream>>>(src, dst, dstBinCount, srcBinCount, E, NB);
    scan_bins_kernel<<<1, 256, 0, stream>>>(
        dstBinCount, srcBinCount, dstBinBase, srcBinBase, dstCursor, srcCursor, NB);
    partition_kernel<<<T, BS, 0, stream>>>(
        src, dst, dstCursor, srcCursor, packed, srcPart, E, NB);
    finalize_kernel<<<2 * NB, BS, 0, stream>>>(
        dstBinBase, srcBinBase, packed, srcPart, csr_src, in_deg, row_start, out_norm, N, NB);
    featw1_kernel<<<(N + 3) / 4, BS, 0, stream>>>(feat, W1, out_norm, featp, N);
    csr_agg1_kernel<<<(int)(((size_t)N * 64 + BS - 1) / BS), BS, 0, stream>>>(
        row_start, in_deg, csr_src, featp, b1, W2, out_norm, s_buf, N);
    csr_agg2_kernel<<<(int)(((size_t)N * 16 + BS - 1) / BS), BS, 0, stream>>>(
        row_start, in_deg, csr_src, s_buf, b2, out, N);
}